// Round 1
// baseline (181.938 us; speedup 1.0000x reference)
//
#include <hip/hip_runtime.h>

#define N_NODES 8000
#define E_EDGES 128000
#define DIM 64
#define NUM_BASES 50
#define R2 400

// ---------------------------------------------------------------------------
// k_relw: rel_weight[r,i,o] = sum_b w_comp[r,b] * weight[b,i,o]
// one block per relation r; 256 threads each produce 4 float4 (16 floats)
// ---------------------------------------------------------------------------
__global__ __launch_bounds__(256) void k_relw(const float* __restrict__ w_comp,
                                              const float* __restrict__ weight,
                                              float* __restrict__ relW) {
    __shared__ float wc[NUM_BASES];
    const int r = blockIdx.x;
    const int t = threadIdx.x;
    if (t < NUM_BASES) wc[t] = w_comp[r * NUM_BASES + t];
    __syncthreads();
    const float4* w4 = (const float4*)weight;           // [50][1024] float4
    float4* out4 = (float4*)(relW + r * 4096);
#pragma unroll
    for (int k = 0; k < 4; ++k) {
        const int idx = k * 256 + t;                    // 0..1023
        float4 acc = make_float4(0.f, 0.f, 0.f, 0.f);
        for (int b = 0; b < NUM_BASES; ++b) {
            const float4 w = w4[b * 1024 + idx];
            const float c = wc[b];
            acc.x = fmaf(c, w.x, acc.x);
            acc.y = fmaf(c, w.y, acc.y);
            acc.z = fmaf(c, w.z, acc.z);
            acc.w = fmaf(c, w.w, acc.w);
        }
        out4[idx] = acc;
    }
}

// ---------------------------------------------------------------------------
// k_edge: per edge e, msg[o] = sum_i feat[src[e],i] * relW[etype[e],i,o]
// one 64-lane wave per edge, lane = o. Atomic accumulate into nei_sum[dst].
// ---------------------------------------------------------------------------
__global__ __launch_bounds__(256) void k_edge(const float* __restrict__ feat,
                                              const float* __restrict__ relW,
                                              const int* __restrict__ src,
                                              const int* __restrict__ dst,
                                              const int* __restrict__ etype,
                                              float* __restrict__ nei_sum,
                                              float* __restrict__ in_deg) {
    const int lane = threadIdx.x & 63;
    const int wid = threadIdx.x >> 6;
    const int e = blockIdx.x * 4 + wid;
    if (e >= E_EDGES) return;
    const int s = src[e];
    const int d = dst[e];
    const int r = etype[e];
    const float fa = feat[s * 64 + lane];               // lane holds feat col
    const float* __restrict__ W = relW + r * 4096;
    float acc = 0.f;
#pragma unroll
    for (int i = 0; i < 64; ++i) {
        const float a = __shfl(fa, i, 64);              // broadcast feat[s,i]
        acc = fmaf(a, W[i * 64 + lane], acc);           // coalesced 256B row
    }
    atomicAdd(&nei_sum[d * 64 + lane], acc);
    if (lane == 0) atomicAdd(&in_deg[d], 1.0f);
}

// ---------------------------------------------------------------------------
// k_node: h = feat@self_loop + nei_sum/max(deg,1); repr = [feat | h]
// one wave per node; self_loop_weight staged in LDS (16 KB).
// ---------------------------------------------------------------------------
__global__ __launch_bounds__(256) void k_node(const float* __restrict__ feat,
                                              const float* __restrict__ slw,
                                              const float* __restrict__ nei_sum,
                                              const float* __restrict__ in_deg,
                                              float* __restrict__ out) {
    __shared__ float s_w[4096];
    const int t = threadIdx.x;
#pragma unroll
    for (int k = 0; k < 16; ++k) s_w[k * 256 + t] = slw[k * 256 + t];
    __syncthreads();
    const int lane = t & 63;
    const int wid = t >> 6;
    const int n = blockIdx.x * 4 + wid;
    if (n >= N_NODES) return;
    const float fa = feat[n * 64 + lane];
    float acc = 0.f;
#pragma unroll
    for (int i = 0; i < 64; ++i) {
        const float a = __shfl(fa, i, 64);
        acc = fmaf(a, s_w[i * 64 + lane], acc);         // 2-way bank alias: free
    }
    const float deg = in_deg[n];
    const float nm = nei_sum[n * 64 + lane] / fmaxf(deg, 1.0f);
    out[n * 128 + lane] = fa;
    out[n * 128 + 64 + lane] = acc + nm;
}

// ---------------------------------------------------------------------------
// k_rel: rel_emb_new[r,j] = sum_k rel_emb[r,k] * W_R_w[j,k] + W_R_b[j]
// one wave per relation row; W_R_w staged TRANSPOSED in LDS.
// ---------------------------------------------------------------------------
__global__ __launch_bounds__(256) void k_rel(const float* __restrict__ rel_emb,
                                             const float* __restrict__ Wr,
                                             const float* __restrict__ br,
                                             float* __restrict__ out) {
    __shared__ float s_wt[4096];                        // s_wt[k*64+j] = Wr[j*64+k]
    const int t = threadIdx.x;
#pragma unroll
    for (int k = 0; k < 16; ++k) {
        const int idx = k * 256 + t;                    // j*64 + kk
        const int j = idx >> 6;
        const int kk = idx & 63;
        s_wt[kk * 64 + j] = Wr[idx];
    }
    __syncthreads();
    const int lane = t & 63;
    const int wid = t >> 6;
    const int r = blockIdx.x * 4 + wid;
    if (r >= R2) return;
    const float re = rel_emb[r * 64 + lane];
    float acc = br[lane];
#pragma unroll
    for (int k = 0; k < 64; ++k) {
        const float a = __shfl(re, k, 64);
        acc = fmaf(a, s_wt[k * 64 + lane], acc);        // 2-way bank alias: free
    }
    out[r * 64 + lane] = acc;
}

// ---------------------------------------------------------------------------
extern "C" void kernel_launch(void* const* d_in, const int* in_sizes, int n_in,
                              void* d_out, int out_size, void* d_ws, size_t ws_size,
                              hipStream_t stream) {
    const float* feat    = (const float*)d_in[0];   // [8000,64]
    const float* rel_emb = (const float*)d_in[1];   // [400,64]
    const float* weight  = (const float*)d_in[2];   // [50,64,64]
    const float* w_comp  = (const float*)d_in[3];   // [400,50]
    const float* slw     = (const float*)d_in[4];   // [64,64]
    const float* Wr      = (const float*)d_in[5];   // [64,64]
    const float* br      = (const float*)d_in[6];   // [64]
    const int*   src     = (const int*)d_in[7];     // [128000]
    const int*   dst     = (const int*)d_in[8];     // [128000]
    const int*   etype   = (const int*)d_in[9];     // [128000]
    float* out = (float*)d_out;

    char* ws = (char*)d_ws;
    float* relW    = (float*)(ws);                        // 6,553,600 B
    float* nei_sum = (float*)(ws + 6553600);              // 2,048,000 B
    float* in_deg  = (float*)(ws + 6553600 + 2048000);    //    32,000 B

    // zero the atomic accumulators every call (ws is poisoned, not re-poisoned)
    hipMemsetAsync(nei_sum, 0, 2048000 + 32000, stream);

    k_relw<<<R2, 256, 0, stream>>>(w_comp, weight, relW);
    k_edge<<<E_EDGES / 4, 256, 0, stream>>>(feat, relW, src, dst, etype,
                                            nei_sum, in_deg);
    k_node<<<N_NODES / 4, 256, 0, stream>>>(feat, slw, nei_sum, in_deg, out);
    k_rel<<<R2 / 4, 256, 0, stream>>>(rel_emb, Wr, br, out + N_NODES * 128);
}